// Round 6
// baseline (631.233 us; speedup 1.0000x reference)
//
#include <hip/hip_runtime.h>
#include <math.h>

#define B_  128
#define P_  2048
#define NB_ 2000
#define NF_ 250
#define NC_ 16
#define R_  128
#define LS_ 1750   // NB-NF (len_sim)
#define NT_ 1751   // NB-NF+1
#define BR_ (B_ * R_)
#define H_  16     // steps per block
#define NBLK_ 110  // number of 16-step blocks covering LS_ (t0 = 0..1744)

typedef int v4i __attribute__((ext_vector_type(4)));

// ---- per-lane f64 2-way select: bit[lane] of m ? b : a ----
__device__ __forceinline__ double dsel_ab(double a, double b, unsigned long long m) {
    long long ab = __double_as_longlong(a), bb = __double_as_longlong(b);
    int rlo, rhi;
    asm("v_cndmask_b32 %0, %2, %4, %6\n\t"
        "v_cndmask_b32 %1, %3, %5, %6"
        : "=&v"(rlo), "=&v"(rhi)
        : "v"((int)ab), "v"((int)(ab >> 32)), "v"((int)bb), "v"((int)(bb >> 32)), "s"(m));
    return __longlong_as_double(((long long)(unsigned)rlo) | ((long long)rhi << 32));
}

// ---- f64 AND with 0/-1 int mask ----
__device__ __forceinline__ double dand(double t, int m) {
    return __longlong_as_double(__double_as_longlong(t) & (long long)m);
}

// ---- reciprocal: v_rcp_f64 + 1 NR (rel err ~1e-16) ----
__device__ __forceinline__ double rcp1(double b) {
    double r;
    asm("v_rcp_f64 %0, %1" : "=v"(r) : "v"(b));
    r = fma(fma(-b, r, 1.0), r, r);
    return r;
}

// ---- custom logit: log(u/(1-u)) f64 path + f32 tail poly, abs err < ~1e-9 ----
__device__ __forceinline__ double logit_fast(float uf) {
    double u = (double)uf;
    double v = 1.0 - u;                  // exact (u has 24-bit mantissa)
    double qd = u * rcp1(v);             // rel err ~2e-16
    long long bits = __double_as_longlong(qd);
    int e = (int)((bits >> 52) & 0x7FF) - 1023;
    double m = __longlong_as_double((bits & 0xFFFFFFFFFFFFFLL) | 0x3FF0000000000000LL);
    if (m > 1.4142135623730951) { m *= 0.5; e += 1; }   // m in [0.707,1.414]
    double s = (m - 1.0) * rcp1(m + 1.0);               // |s| <= 0.1716, (m-1) exact
    float zf = (float)(s * s);
    float Qf = fmaf(zf, fmaf(zf, fmaf(zf, fmaf(zf,
        0.09090909090909091f, 0.1111111111111111f),
        0.14285714285714285f), 0.2f), 0.3333333333333333f);
    double logm = fma(2.0 * s, (double)(zf * Qf), 2.0 * s);   // 2*atanh(s)
    return fma((double)e, 0.6931471805599453, logm);
}

// ---------------- fused: ft (blocks 0..6) + sdot (blocks 7..134) ----------------
__global__ __launch_bounds__(256) void k_pre(const float* __restrict__ st,
                                             const float* __restrict__ stf,
                                             const float* __restrict__ sp,
                                             const float* __restrict__ sf,
                                             double* __restrict__ ft,
                                             double* __restrict__ sdot) {
    if (blockIdx.x < 7) {
        int t = blockIdx.x * 256 + threadIdx.x;
        if (t >= NT_) return;
        double s = 0.0;
        for (int k = 0; k < NF_; ++k) s += (double)st[t + k] * (double)stf[k];
        ft[t] = s;
    } else {
        __shared__ double red[256];
        int b = blockIdx.x - 7;
        double s = 0.0;
        for (int p = threadIdx.x; p < P_; p += 256)
            s += (double)sp[(size_t)b * P_ + p] * (double)sf[p];
        red[threadIdx.x] = s;
        __syncthreads();
        for (int off = 128; off > 0; off >>= 1) {
            if (threadIdx.x < off) red[threadIdx.x] += red[threadIdx.x + off];
            __syncthreads();
        }
        if (threadIdx.x == 0) sdot[b] = red[0];
    }
}

// ---------------- gensig[b,t] = sdot[b]*ft[t] + bias + coup[b,t], f64 ----------------
__global__ __launch_bounds__(256) void k_coup(const float* __restrict__ cc,
                                              const float* __restrict__ cf,
                                              const double* __restrict__ sdot,
                                              const double* __restrict__ ft,
                                              const float* __restrict__ bias,
                                              double* __restrict__ gensig) {
    __shared__ __align__(16) float  ccs[NC_ * 512];   // 32 KB
    __shared__ __align__(16) double cfs[NC_ * 256];   // 32 KB
    __shared__ double red[3][64][4];                  // 6 KB
    int b = blockIdx.y, t0 = blockIdx.x * 256;
    int tid = threadIdx.x, lane = tid & 63, wv = tid >> 6;

    for (int idx = tid; idx < NC_ * 128; idx += 256) {
        int c = idx >> 7, j4 = (idx & 127) * 4, src = t0 + j4;
        const float* p = cc + ((size_t)b * NC_ + c) * NB_ + src;
        float4 v;
        if (src + 3 < NB_) v = *(const float4*)p;
        else {
            v.x = (src     < NB_) ? p[0] : 0.f;
            v.y = (src + 1 < NB_) ? p[1] : 0.f;
            v.z = (src + 2 < NB_) ? p[2] : 0.f;
            v.w = (src + 3 < NB_) ? p[3] : 0.f;
        }
        *(float4*)&ccs[c * 512 + j4] = v;
    }
    for (int idx = tid; idx < NC_ * 256; idx += 256) {
        int c = idx >> 8, k = idx & 255;
        cfs[idx] = (k < NF_) ? (double)cf[c * NF_ + k] : 0.0;
    }
    __syncthreads();

    double a0 = 0, a1 = 0, a2 = 0, a3 = 0;
    int base = lane * 4;
    for (int c = wv; c < NC_; c += 4) {
        const float*  row  = &ccs[c * 512];
        const double* crow = &cfs[c * 256];
        float4 cur = *(const float4*)&row[base];
        for (int k4 = 0; k4 < 252; k4 += 4) {
            float4 nxt = *(const float4*)&row[base + k4 + 4];
            double e0 = cur.x, e1 = cur.y, e2 = cur.z, e3 = cur.w;
            double e4 = nxt.x, e5 = nxt.y, e6 = nxt.z;
            double c0 = crow[k4], c1 = crow[k4 + 1], c2 = crow[k4 + 2], c3 = crow[k4 + 3];
            a0 += e0 * c0 + e1 * c1 + e2 * c2 + e3 * c3;
            a1 += e1 * c0 + e2 * c1 + e3 * c2 + e4 * c3;
            a2 += e2 * c0 + e3 * c1 + e4 * c2 + e5 * c3;
            a3 += e3 * c0 + e4 * c1 + e5 * c2 + e6 * c3;
            cur = nxt;
        }
    }
    if (wv > 0) {
        red[wv - 1][lane][0] = a0; red[wv - 1][lane][1] = a1;
        red[wv - 1][lane][2] = a2; red[wv - 1][lane][3] = a3;
    }
    __syncthreads();
    if (wv == 0) {
        a0 += red[0][lane][0] + red[1][lane][0] + red[2][lane][0];
        a1 += red[0][lane][1] + red[1][lane][1] + red[2][lane][1];
        a2 += red[0][lane][2] + red[1][lane][2] + red[2][lane][2];
        a3 += red[0][lane][3] + red[1][lane][3] + red[2][lane][3];
        double gb = (double)bias[0];
        double sd = sdot[b];
        double accs[4] = {a0, a1, a2, a3};
        int tb = t0 + base;
        for (int i = 0; i < 4; ++i) {
            int t = tb + i;
            if (t < LS_) gensig[(size_t)b * LS_ + t] = sd * ft[t] + gb + accs[i];
        }
    }
}

// ---------------- scan: partial/delta i8-MFMA far + 4-level spec rounds ----
// Waves 0..3 (scan): one wave per 16 chains. Waves 4..7 (prep): logit producers.
// NEAR v3: per round the ONLY on-chain work is: 4-level int cndmask tree
//   (A4..A7 masks select the T4..T7 combo from a 16-entry table) -> 1 f64 sub
//   -> 8 f64 cmps -> ballots -> SALU cascade. Ages 8..15 (xb8, f64 tree) are
//   computed ONE ROUND EARLY from q16 (they only touch rounds <= E-2); age 7
//   enters via the A7 mask (pure SALU shifts of the saved round masks S_E).
//   Per-chain spike nibbles extracted off-chain: qn = (S_E >> 4*cn) & 15.
// TAIL: ds_bpermute eliminated - chain lw's 16 bits rebuilt from S_0..S_3.
__global__ __launch_bounds__(512, 2) void k_scan(const double* __restrict__ gensig,
                                                 const float* __restrict__ u,
                                                 const float* __restrict__ iss,
                                                 const float* __restrict__ ff,
                                                 float* __restrict__ out) {
    __shared__ double farT_all[4][16 * 17];          // 8.5 KB (scan waves only)
    __shared__ double luring[2][4][4 * 64];          // 16 KB: [slot][scanwave][e*64+lane]
    int tid = threadIdx.x;
    int wv = tid >> 6, l = tid & 63;
    int swv = wv & 3;
    const bool isPrep = (wv >= 4);
    int gw = blockIdx.x * 4 + swv;
    int b = gw >> 3, rbase = (gw & 7) * 16;
    double* farT = &farT_all[swv][0];

    int lw = l & 15;
    int q  = l >> 4;
    int cn = l >> 2;
    int j  = l & 3;
    int jo = 16 + j;            // sbfe offset base
    int sh4cn = cn * 4;         // = l & 60
    int sh4lw = lw * 4;

    const unsigned long long COL0_ = 0x1111111111111111ull;
    const unsigned long long COL1_ = COL0_ << 1;
    const unsigned long long COL2_ = COL0_ << 2;
    const unsigned long long COL3_ = COL0_ << 3;
    const unsigned long long COL01_ = COL0_ | COL1_;

    const double* gs   = gensig + (size_t)b * LS_;
    const float*  up   = u + b * R_ + rbase + cn;
    float*        op   = out + ((size_t)(b * R_ + rbase + cn)) * NB_ + NF_;
    const float*  issb = iss + b * NF_;

    // scan-wave state
    unsigned long long W0 = 0, W1 = 0, W2 = 0, W3 = 0;
    v4i Bf[4][6];
    double tp8 = 0, tp9 = 0, tp10 = 0, tp11 = 0, tp12 = 0, tp13 = 0, tp14 = 0, tp15 = 0;
    double SC1 = 0, SC2 = 0, SC3 = 0, SC4 = 0, SC5 = 0, SC6 = 0, SC7 = 0;
    double Cc0 = 0, Cc1 = 0, Cc2 = 0, Cc3 = 0, Cc4 = 0, Cc5 = 0, Cc6 = 0, Cc7 = 0;
    double Cc8 = 0, Cc9 = 0, Cc10 = 0, Cc11 = 0, Cc12 = 0, Cc13 = 0, Cc14 = 0, Cc15 = 0;
    double thr0 = 0, thr1 = 0, thr2 = 0, thr3 = 0;
    double gprep = 0.0;
    // prep-wave state
    float ur0 = 0.f, ur1 = 0.f, ur2 = 0.f, ur3 = 0.f;

    if (!isPrep) {
        // ---- iss -> out[.., 0:250] ----
        for (int idx = l; idx < 16 * NF_; idx += 64) {
            int c = idx / NF_, k = idx - c * NF_;
            out[((size_t)(b * R_ + rbase + c)) * NB_ + k] = issb[k];
        }
        // ---- window: bit k = spike(t0-250+k) ----
        for (int k = 0; k < NF_; ++k) {
            unsigned long long bit = (issb[k] > 0.5f) ? 1ull : 0ull;
            if      (k <  64) W0 |= bit << k;
            else if (k < 128) W1 |= bit << (k - 64);
            else if (k < 192) W2 |= bit << (k - 128);
            else              W3 |= bit << (k - 192);
        }
        // ---- B: F[k][n] = ff[k-n]; 6 signed base-256 digit planes @2^48 ----
        int Bword[4][6][4];
#pragma unroll
        for (int kc = 0; kc < 4; ++kc)
#pragma unroll
            for (int p = 0; p < 6; ++p)
#pragma unroll
                for (int w = 0; w < 4; ++w) Bword[kc][p][w] = 0;
#pragma unroll
        for (int kc = 0; kc < 4; ++kc) {
#pragma unroll
            for (int jj = 0; jj < 16; ++jj) {
                int k = kc * 64 + q * 16 + jj;
                int idx = k - lw;
                long long v = 0;
                if (idx >= 0 && idx < NF_)
                    v = __double2ll_rn((double)ff[idx] * 281474976710656.0);   // * 2^48
#pragma unroll
                for (int p = 0; p < 6; ++p) {
                    int d = (int)((v + 128) & 255) - 128;
                    v = (v - (long long)d) >> 8;
                    Bword[kc][p][jj >> 2] |= (d & 255) << ((jj & 3) * 8);
                }
            }
        }
#pragma unroll
        for (int kc = 0; kc < 4; ++kc)
#pragma unroll
            for (int p = 0; p < 6; ++p) {
                v4i t; t.x = Bword[kc][p][0]; t.y = Bword[kc][p][1];
                t.z = Bword[kc][p][2]; t.w = Bword[kc][p][3];
                Bf[kc][p] = t;
            }
        // near taps, f64: age a -> ff[250-a]
        double T1d = (double)ff[249], T2d = (double)ff[248], T3d = (double)ff[247];
        double T4d = (double)ff[246], T5d = (double)ff[245], T6d = (double)ff[244];
        double T7d = (double)ff[243];
        tp8  = (double)ff[242]; tp9  = (double)ff[241];
        tp10 = (double)ff[240]; tp11 = (double)ff[239]; tp12 = (double)ff[238];
        tp13 = (double)ff[237]; tp14 = (double)ff[236]; tp15 = (double)ff[235];
        // speculation compare constants (ages 1..3; bit0=T1,bit1=T2,bit2=T3)
        SC1 = T1d; SC2 = T2d; SC3 = T1d + T2d;
        SC4 = T3d; SC5 = T3d + T1d; SC6 = T3d + T2d; SC7 = (T3d + T2d) + T1d;
        // base select table (ages 4..7; bit0=A4/T4, bit1=A5/T5, bit2=A6/T6, bit3=A7/T7)
        Cc0  = 0.0;        Cc1  = T4d;        Cc2  = T5d;        Cc3  = T4d + T5d;
        Cc4  = T6d;        Cc5  = T6d + T4d;  Cc6  = T6d + T5d;  Cc7  = (T6d + T5d) + T4d;
        Cc8  = T7d;        Cc9  = T7d + Cc1;  Cc10 = T7d + Cc2;  Cc11 = T7d + Cc3;
        Cc12 = T7d + Cc4;  Cc13 = T7d + Cc5;  Cc14 = T7d + Cc6;  Cc15 = T7d + Cc7;
    } else {
        // ---- prep prologue: lu(0) -> slot0, lu(1) -> slot1, prefetch u(block 2) ----
        ur0 = up[(size_t)(0  + j) * BR_];
        ur1 = up[(size_t)(4  + j) * BR_];
        ur2 = up[(size_t)(8  + j) * BR_];
        ur3 = up[(size_t)(12 + j) * BR_];
        luring[0][swv][  0 + l] = logit_fast(ur0);
        luring[0][swv][ 64 + l] = logit_fast(ur1);
        luring[0][swv][128 + l] = logit_fast(ur2);
        luring[0][swv][192 + l] = logit_fast(ur3);
        ur0 = up[(size_t)(16 + j) * BR_];
        ur1 = up[(size_t)(20 + j) * BR_];
        ur2 = up[(size_t)(24 + j) * BR_];
        ur3 = up[(size_t)(28 + j) * BR_];
        luring[1][swv][  0 + l] = logit_fast(ur0);
        luring[1][swv][ 64 + l] = logit_fast(ur1);
        luring[1][swv][128 + l] = logit_fast(ur2);
        luring[1][swv][192 + l] = logit_fast(ur3);
        ur0 = up[(size_t)(32 + j) * BR_];
        ur1 = up[(size_t)(36 + j) * BR_];
        ur2 = up[(size_t)(40 + j) * BR_];
        ur3 = up[(size_t)(44 + j) * BR_];
    }

    // full-window far (prologue only): fb[chain=q*4+r][step=lw]
    auto do_far = [&](double gp) {
        unsigned long long Sarr[4] = {W0, W1, W2, W3};
        v4i accm[6];
#pragma unroll
        for (int p = 0; p < 6; ++p) accm[p] = (v4i){0, 0, 0, 0};
#pragma unroll
        for (int kc = 0; kc < 4; ++kc) {
            unsigned f = (unsigned)((Sarr[kc] >> (q * 16)) & 0xFFFFull);
            v4i av;
            av.x = (int)((((f      ) & 0xFu) * 0x00204081u) & 0x01010101u);
            av.y = (int)((((f >>  4) & 0xFu) * 0x00204081u) & 0x01010101u);
            av.z = (int)((((f >>  8) & 0xFu) * 0x00204081u) & 0x01010101u);
            av.w = (int)((((f >> 12) & 0xFu) * 0x00204081u) & 0x01010101u);
#pragma unroll
            for (int p = 0; p < 6; ++p)
                accm[p] = __builtin_amdgcn_mfma_i32_16x16x64_i8(av, Bf[kc][p], accm[p], 0, 0, 0);
        }
#pragma unroll
        for (int r = 0; r < 4; ++r) {
            int lo = accm[0][r] + accm[1][r] * 256 + accm[2][r] * 65536;
            int hi = accm[3][r] + accm[4][r] * 256 + accm[5][r] * 65536;
            double fb = gp + (double)lo * 0x1p-48 + (double)hi * 0x1p-24;
            farT[(q * 4 + r) * 17 + lw] = fb;
        }
    };

    // ages 8..15 partial sum for round E (q16v bit i = step i; reads steps <= 4E-5)
    auto xb8 = [&](int e4, unsigned q16v) -> double {
        unsigned qs = (q16v << 16) >> e4;
        double x = (dand(tp8,  __builtin_amdgcn_sbfe((int)qs, jo - 8,  1)) +
                    dand(tp9,  __builtin_amdgcn_sbfe((int)qs, jo - 9,  1))) +
                   (dand(tp10, __builtin_amdgcn_sbfe((int)qs, jo - 10, 1)) +
                    dand(tp11, __builtin_amdgcn_sbfe((int)qs, jo - 11, 1)));
        double y = (dand(tp12, __builtin_amdgcn_sbfe((int)qs, jo - 12, 1)) +
                    dand(tp13, __builtin_amdgcn_sbfe((int)qs, jo - 13, 1))) +
                   (dand(tp14, __builtin_amdgcn_sbfe((int)qs, jo - 14, 1)) +
                    dand(tp15, __builtin_amdgcn_sbfe((int)qs, jo - 15, 1)));
        return x + y;
    };

    __syncthreads();   // A: prep's lu(0), lu(1) visible to scan waves

    if (!isPrep) {
        // ---- scan prologue: block 0 ----
        gprep = gs[lw];
        do_far(gprep);
        double lu0 = luring[0][swv][  0 + l];
        double lu1 = luring[0][swv][ 64 + l];
        double lu2 = luring[0][swv][128 + l];
        double lu3 = luring[0][swv][192 + l];
        __asm__ volatile("s_waitcnt lgkmcnt(0)" ::: "memory");
        thr0 = lu0 - farT[cn * 17 +  0 + j];
        thr1 = lu1 - farT[cn * 17 +  4 + j];
        thr2 = lu2 - farT[cn * 17 +  8 + j];
        thr3 = lu3 - farT[cn * 17 + 12 + j];
        { int tg = 16 + lw; if (tg > LS_ - 1) tg = LS_ - 1; gprep = gs[tg]; }
    }

    __syncthreads();   // B: scan's slot0 (lu(0)) reads done before prep overwrites it

// one 4-step round: E = round, PRE2 = thr_E - xb8_E (precomputed), A7M = age-7 mask
#define ROUND(PRE2, A7M, SOUT) { \
    double u0_ = dsel_ab(Cc0,  Cc1,  A4); \
    double u1_ = dsel_ab(Cc2,  Cc3,  A4); \
    double u2_ = dsel_ab(Cc4,  Cc5,  A4); \
    double u3_ = dsel_ab(Cc6,  Cc7,  A4); \
    double u4_ = dsel_ab(Cc8,  Cc9,  A4); \
    double u5_ = dsel_ab(Cc10, Cc11, A4); \
    double u6_ = dsel_ab(Cc12, Cc13, A4); \
    double u7_ = dsel_ab(Cc14, Cc15, A4); \
    double v0_ = dsel_ab(u0_, u1_, A5); \
    double v1_ = dsel_ab(u2_, u3_, A5); \
    double v2_ = dsel_ab(u4_, u5_, A5); \
    double v3_ = dsel_ab(u6_, u7_, A5); \
    double w0_ = dsel_ab(v0_, v1_, A6); \
    double w1_ = dsel_ab(v2_, v3_, A6); \
    double sel_ = dsel_ab(w0_, w1_, (A7M)); \
    double rhs_ = (PRE2) - sel_; \
    unsigned long long Bm0 = __ballot(0.0 > rhs_); \
    unsigned long long Bm1 = __ballot(SC1 > rhs_); \
    unsigned long long Bm2 = __ballot(SC2 > rhs_); \
    unsigned long long Bm3 = __ballot(SC3 > rhs_); \
    unsigned long long Bm4 = __ballot(SC4 > rhs_); \
    unsigned long long Bm5 = __ballot(SC5 > rhs_); \
    unsigned long long Bm6 = __ballot(SC6 > rhs_); \
    unsigned long long Bm7 = __ballot(SC7 > rhs_); \
    unsigned long long a3p = P >> 1, a2p = P >> 2; \
    unsigned long long C0 = Bm0 ^ (a3p & (Bm4 ^ Bm0)); \
    unsigned long long C1 = Bm1 ^ (a3p & (Bm5 ^ Bm1)); \
    unsigned long long C2 = Bm2 ^ (a3p & (Bm6 ^ Bm2)); \
    unsigned long long C3 = Bm3 ^ (a3p & (Bm7 ^ Bm3)); \
    unsigned long long D0 = C0 ^ (a2p & (C2 ^ C0)); \
    unsigned long long D1 = C1 ^ (a2p & (C3 ^ C1)); \
    unsigned long long Dd = D1 ^ D0; \
    unsigned long long S = (D0 ^ ((P >> 3) & Dd)) & COL0_; \
    S |= (D0 ^ ((S << 1) & Dd)) & COL1_; \
    { unsigned long long a2s = S << 2; \
      unsigned long long D0b = C0 ^ (a2s & (C2 ^ C0)); \
      unsigned long long D1b = C1 ^ (a2s & (C3 ^ C1)); \
      S |= (D0b ^ ((S << 1) & (D1b ^ D0b))) & COL2_; } \
    { unsigned long long a3s = S << 3, a2s = S << 2; \
      unsigned long long C0c = Bm0 ^ (a3s & (Bm4 ^ Bm0)); \
      unsigned long long C1c = Bm1 ^ (a3s & (Bm5 ^ Bm1)); \
      unsigned long long C2c = Bm2 ^ (a3s & (Bm6 ^ Bm2)); \
      unsigned long long C3c = Bm3 ^ (a3s & (Bm7 ^ Bm3)); \
      unsigned long long D0c = C0c ^ (a2s & (C2c ^ C0c)); \
      unsigned long long D1c = C1c ^ (a2s & (C3c ^ C1c)); \
      S |= (D0c ^ ((S << 1) & (D1c ^ D0c))) & COL3_; } \
    (SOUT) = S; \
    A4 = S; \
    A5 = ((S << 1) & ~COL0_) | ((P >> 3) & COL0_); \
    A6 = ((S << 2) & ~COL01_) | ((P >> 2) & COL01_); \
    P = S; \
}

    int blk = 0;
    for (int t0 = 0; t0 < LS_; t0 += H_, ++blk) {
        if (!isPrep) {
            bool more = (t0 + H_ < LS_);
            // ---- top: shifted window; issue partial far MFMAs (run under near) ----
            unsigned long long Ws0 = (W0 >> 16) | (W1 << 48);
            unsigned long long Ws1 = (W1 >> 16) | (W2 << 48);
            unsigned long long Ws2 = (W2 >> 16) | (W3 << 48);
            unsigned long long Ws3 = (W3 >> 16);
            v4i accm[6];
#pragma unroll
            for (int p = 0; p < 6; ++p) accm[p] = (v4i){0, 0, 0, 0};
            if (more) {
                unsigned long long Sarr[4] = {Ws0, Ws1, Ws2, Ws3};
#pragma unroll
                for (int kc = 0; kc < 4; ++kc) {
                    unsigned f = (unsigned)((Sarr[kc] >> (q * 16)) & 0xFFFFull);
                    v4i av;
                    av.x = (int)((((f      ) & 0xFu) * 0x00204081u) & 0x01010101u);
                    av.y = (int)((((f >>  4) & 0xFu) * 0x00204081u) & 0x01010101u);
                    av.z = (int)((((f >>  8) & 0xFu) * 0x00204081u) & 0x01010101u);
                    av.w = (int)((((f >> 12) & 0xFu) * 0x00204081u) & 0x01010101u);
#pragma unroll
                    for (int p = 0; p < 6; ++p)
                        accm[p] = __builtin_amdgcn_mfma_i32_16x16x64_i8(av, Bf[kc][p], accm[p], 0, 0, 0);
                }
            }

            // ---- NEAR: 4 rounds; xb8/A7 hoisted one round early ----
            unsigned long long P = 0, A4 = 0, A5 = 0, A6 = 0;
            unsigned long long S0s, S1s, S2s, S3s;
            unsigned q16;
            ROUND(thr0, 0ull, S0s)
            q16 = ((unsigned)(S0s >> sh4cn)) & 15u;
            unsigned long long A7_1 = (S0s << 3) & COL3_;
            double pre2_2 = thr2 - xb8(8, q16);            // overlaps round 1
            ROUND(thr1, A7_1, S1s)
            q16 |= (((unsigned)(S1s >> sh4cn)) & 15u) << 4;
            unsigned long long A7_2 = ((S0s >> 1) & ~COL3_) | ((S1s << 3) & COL3_);
            double pre2_3 = thr3 - xb8(12, q16);           // overlaps round 2
            ROUND(pre2_2, A7_2, S2s)
            q16 |= (((unsigned)(S2s >> sh4cn)) & 15u) << 8;
            unsigned long long A7_3 = ((S1s >> 1) & ~COL3_) | ((S2s << 3) & COL3_);
            ROUND(pre2_3, A7_3, S3s)
            q16 |= (((unsigned)(S3s >> sh4cn)) & 15u) << 12;
            unsigned q2 = q16;                             // bit i = spike(t0+i), chain cn

            // ---- store spikes (fire-and-forget) ----
            int rem = LS_ - t0; if (rem > H_) rem = H_;
            int s0 = 4 * j;
            if (s0 + 3 < rem) {
                float4 o;
                o.x = (float)((q2 >> (s0    )) & 1u);
                o.y = (float)((q2 >> (s0 + 1)) & 1u);
                o.z = (float)((q2 >> (s0 + 2)) & 1u);
                o.w = (float)((q2 >> (s0 + 3)) & 1u);
                *(float4*)(op + t0 + s0) = o;
            } else {
#pragma unroll
                for (int e = 0; e < 4; ++e)
                    if (s0 + e < rem) op[t0 + s0 + e] = (float)((q2 >> (s0 + e)) & 1u);
            }

            if (more) {
                // chain lw's 16 new spike bits, rebuilt from SGPR masks (no LDS)
                unsigned q2n32 = (((unsigned)(S0s >> sh4lw)) & 15u)
                               | ((((unsigned)(S1s >> sh4lw)) & 15u) << 4)
                               | ((((unsigned)(S2s >> sh4lw)) & 15u) << 8)
                               | ((((unsigned)(S3s >> sh4lw)) & 15u) << 12);

                // lu(blk+1) was written by prep last iteration; issue reads early
                double lu0 = luring[(blk + 1) & 1][swv][  0 + l];
                double lu1 = luring[(blk + 1) & 1][swv][ 64 + l];
                double lu2 = luring[(blk + 1) & 1][swv][128 + l];
                double lu3 = luring[(blk + 1) & 1][swv][192 + l];

                // ---- delta far: this block's 16 spikes at window bits 234..249 ----
                unsigned long long W3d = ((unsigned long long)q2n32) << 42;
                unsigned fd = (unsigned)((W3d >> (q * 16)) & 0xFFFFull);
                v4i avd;
                avd.x = (int)((((fd      ) & 0xFu) * 0x00204081u) & 0x01010101u);
                avd.y = (int)((((fd >>  4) & 0xFu) * 0x00204081u) & 0x01010101u);
                avd.z = (int)((((fd >>  8) & 0xFu) * 0x00204081u) & 0x01010101u);
                avd.w = (int)((((fd >> 12) & 0xFu) * 0x00204081u) & 0x01010101u);
#pragma unroll
                for (int p = 0; p < 6; ++p)
                    accm[p] = __builtin_amdgcn_mfma_i32_16x16x64_i8(avd, Bf[3][p], accm[p], 0, 0, 0);

#pragma unroll
                for (int r = 0; r < 4; ++r) {
                    int lo = accm[0][r] + accm[1][r] * 256 + accm[2][r] * 65536;
                    int hi = accm[3][r] + accm[4][r] * 256 + accm[5][r] * 65536;
                    double fb = gprep + (double)lo * 0x1p-48 + (double)hi * 0x1p-24;
                    farT[(q * 4 + r) * 17 + lw] = fb;
                }
                __asm__ volatile("s_waitcnt lgkmcnt(0)" ::: "memory");
                thr0 = lu0 - farT[cn * 17 +  0 + j];
                thr1 = lu1 - farT[cn * 17 +  4 + j];
                thr2 = lu2 - farT[cn * 17 +  8 + j];
                thr3 = lu3 - farT[cn * 17 + 12 + j];

                // commit window for next block
                W0 = Ws0; W1 = Ws1; W2 = Ws2; W3 = Ws3 | W3d;

                int tg = t0 + 32 + lw; if (tg > LS_ - 1) tg = LS_ - 1;
                gprep = gs[tg];
            }
        } else {
            // ---- prep: lu(blk+2) -> slot[blk&1]; prefetch u(block blk+3) ----
            if (blk <= NBLK_ - 3) {
                double lu0 = logit_fast(ur0), lu1 = logit_fast(ur1);
                double lu2 = logit_fast(ur2), lu3 = logit_fast(ur3);
                luring[blk & 1][swv][  0 + l] = lu0;
                luring[blk & 1][swv][ 64 + l] = lu1;
                luring[blk & 1][swv][128 + l] = lu2;
                luring[blk & 1][swv][192 + l] = lu3;
                if (blk <= NBLK_ - 4) {
                    int T = (blk + 3) * H_;
                    int t_;
                    t_ = T +  0 + j; if (t_ > LS_ - 1) t_ = LS_ - 1; ur0 = up[(size_t)t_ * BR_];
                    t_ = T +  4 + j; if (t_ > LS_ - 1) t_ = LS_ - 1; ur1 = up[(size_t)t_ * BR_];
                    t_ = T +  8 + j; if (t_ > LS_ - 1) t_ = LS_ - 1; ur2 = up[(size_t)t_ * BR_];
                    t_ = T + 12 + j; if (t_ > LS_ - 1) t_ = LS_ - 1; ur3 = up[(size_t)t_ * BR_];
                }
            }
        }
        __syncthreads();   // paces ring: write(t) | bar | read(t+1) | bar | overwrite(t+2)
    }
#undef ROUND
}

extern "C" void kernel_launch(void* const* d_in, const int* in_sizes, int n_in,
                              void* d_out, int out_size, void* d_ws, size_t ws_size,
                              hipStream_t stream) {
    const float* stim_spat = (const float*)d_in[0];   // (128,2048)
    const float* stim_time = (const float*)d_in[1];   // (2000,)
    const float* iss       = (const float*)d_in[2];   // (128,250)
    const float* cc        = (const float*)d_in[3];   // (128,16,2000)
    const float* sf        = (const float*)d_in[4];   // (2048,)
    const float* bias      = (const float*)d_in[5];   // (1,)
    const float* stf       = (const float*)d_in[6];   // (250,)
    const float* ff        = (const float*)d_in[7];   // (250,)
    const float* cf        = (const float*)d_in[8];   // (16,250)
    const float* u         = (const float*)d_in[9];   // (1750,128,128)
    (void)in_sizes; (void)n_in; (void)out_size; (void)ws_size;

    float* out = (float*)d_out;                       // (128,128,2000)

    double* ws     = (double*)d_ws;
    double* gensig = ws;                              // 128*1750 f64
    double* ft     = gensig + (size_t)B_ * LS_;       // 1751 f64
    double* sdot   = ft + NT_;                        // 128 f64

    k_pre  <<<135, 256, 0, stream>>>(stim_time, stf, stim_spat, sf, ft, sdot);
    k_coup <<<dim3(7, B_), 256, 0, stream>>>(cc, cf, sdot, ft, bias, gensig);
    k_scan <<<B_ * 2, 512, 0, stream>>>(gensig, u, iss, ff, out);
}

// Round 7
// 516.702 us; speedup vs baseline: 1.2217x; 1.2217x over previous
//
#include <hip/hip_runtime.h>
#include <math.h>

#define B_  128
#define P_  2048
#define NB_ 2000
#define NF_ 250
#define NC_ 16
#define R_  128
#define LS_ 1750   // NB-NF (len_sim)
#define NT_ 1751   // NB-NF+1
#define BR_ (B_ * R_)
#define H_  16     // steps per block
#define NBLK_ 110  // number of 16-step blocks covering LS_ (t0 = 0..1744)

typedef int v4i __attribute__((ext_vector_type(4)));

// ---- per-lane f64 2-way select: bit[lane] of m ? b : a ----
__device__ __forceinline__ double dsel_ab(double a, double b, unsigned long long m) {
    long long ab = __double_as_longlong(a), bb = __double_as_longlong(b);
    int rlo, rhi;
    asm("v_cndmask_b32 %0, %2, %4, %6\n\t"
        "v_cndmask_b32 %1, %3, %5, %6"
        : "=&v"(rlo), "=&v"(rhi)
        : "v"((int)ab), "v"((int)(ab >> 32)), "v"((int)bb), "v"((int)(bb >> 32)), "s"(m));
    return __longlong_as_double(((long long)(unsigned)rlo) | ((long long)rhi << 32));
}

// ---- f64 AND with 0/-1 int mask ----
__device__ __forceinline__ double dand(double t, int m) {
    return __longlong_as_double(__double_as_longlong(t) & (long long)m);
}

// ---- reciprocal: v_rcp_f64 + 1 NR (rel err ~1e-16) ----
__device__ __forceinline__ double rcp1(double b) {
    double r;
    asm("v_rcp_f64 %0, %1" : "=v"(r) : "v"(b));
    r = fma(fma(-b, r, 1.0), r, r);
    return r;
}

// ---- custom logit: log(u/(1-u)) f64 path + f32 tail poly, abs err < ~1e-9 ----
__device__ __forceinline__ double logit_fast(float uf) {
    double u = (double)uf;
    double v = 1.0 - u;                  // exact (u has 24-bit mantissa)
    double qd = u * rcp1(v);             // rel err ~2e-16
    long long bits = __double_as_longlong(qd);
    int e = (int)((bits >> 52) & 0x7FF) - 1023;
    double m = __longlong_as_double((bits & 0xFFFFFFFFFFFFFLL) | 0x3FF0000000000000LL);
    if (m > 1.4142135623730951) { m *= 0.5; e += 1; }   // m in [0.707,1.414]
    double s = (m - 1.0) * rcp1(m + 1.0);               // |s| <= 0.1716, (m-1) exact
    float zf = (float)(s * s);
    float Qf = fmaf(zf, fmaf(zf, fmaf(zf, fmaf(zf,
        0.09090909090909091f, 0.1111111111111111f),
        0.14285714285714285f), 0.2f), 0.3333333333333333f);
    double logm = fma(2.0 * s, (double)(zf * Qf), 2.0 * s);   // 2*atanh(s)
    return fma((double)e, 0.6931471805599453, logm);
}

// ---------------- fused: ft (blocks 0..6) + sdot (blocks 7..134) ----------------
__global__ __launch_bounds__(256) void k_pre(const float* __restrict__ st,
                                             const float* __restrict__ stf,
                                             const float* __restrict__ sp,
                                             const float* __restrict__ sf,
                                             double* __restrict__ ft,
                                             double* __restrict__ sdot) {
    if (blockIdx.x < 7) {
        int t = blockIdx.x * 256 + threadIdx.x;
        if (t >= NT_) return;
        double s = 0.0;
        for (int k = 0; k < NF_; ++k) s += (double)st[t + k] * (double)stf[k];
        ft[t] = s;
    } else {
        __shared__ double red[256];
        int b = blockIdx.x - 7;
        double s = 0.0;
        for (int p = threadIdx.x; p < P_; p += 256)
            s += (double)sp[(size_t)b * P_ + p] * (double)sf[p];
        red[threadIdx.x] = s;
        __syncthreads();
        for (int off = 128; off > 0; off >>= 1) {
            if (threadIdx.x < off) red[threadIdx.x] += red[threadIdx.x + off];
            __syncthreads();
        }
        if (threadIdx.x == 0) sdot[b] = red[0];
    }
}

// ---------------- gensig[b,t] = sdot[b]*ft[t] + bias + coup[b,t], f64 ----------------
__global__ __launch_bounds__(256) void k_coup(const float* __restrict__ cc,
                                              const float* __restrict__ cf,
                                              const double* __restrict__ sdot,
                                              const double* __restrict__ ft,
                                              const float* __restrict__ bias,
                                              double* __restrict__ gensig) {
    __shared__ __align__(16) float  ccs[NC_ * 512];   // 32 KB
    __shared__ __align__(16) double cfs[NC_ * 256];   // 32 KB
    __shared__ double red[3][64][4];                  // 6 KB
    int b = blockIdx.y, t0 = blockIdx.x * 256;
    int tid = threadIdx.x, lane = tid & 63, wv = tid >> 6;

    for (int idx = tid; idx < NC_ * 128; idx += 256) {
        int c = idx >> 7, j4 = (idx & 127) * 4, src = t0 + j4;
        const float* p = cc + ((size_t)b * NC_ + c) * NB_ + src;
        float4 v;
        if (src + 3 < NB_) v = *(const float4*)p;
        else {
            v.x = (src     < NB_) ? p[0] : 0.f;
            v.y = (src + 1 < NB_) ? p[1] : 0.f;
            v.z = (src + 2 < NB_) ? p[2] : 0.f;
            v.w = (src + 3 < NB_) ? p[3] : 0.f;
        }
        *(float4*)&ccs[c * 512 + j4] = v;
    }
    for (int idx = tid; idx < NC_ * 256; idx += 256) {
        int c = idx >> 8, k = idx & 255;
        cfs[idx] = (k < NF_) ? (double)cf[c * NF_ + k] : 0.0;
    }
    __syncthreads();

    double a0 = 0, a1 = 0, a2 = 0, a3 = 0;
    int base = lane * 4;
    for (int c = wv; c < NC_; c += 4) {
        const float*  row  = &ccs[c * 512];
        const double* crow = &cfs[c * 256];
        float4 cur = *(const float4*)&row[base];
        for (int k4 = 0; k4 < 252; k4 += 4) {
            float4 nxt = *(const float4*)&row[base + k4 + 4];
            double e0 = cur.x, e1 = cur.y, e2 = cur.z, e3 = cur.w;
            double e4 = nxt.x, e5 = nxt.y, e6 = nxt.z;
            double c0 = crow[k4], c1 = crow[k4 + 1], c2 = crow[k4 + 2], c3 = crow[k4 + 3];
            a0 += e0 * c0 + e1 * c1 + e2 * c2 + e3 * c3;
            a1 += e1 * c0 + e2 * c1 + e3 * c2 + e4 * c3;
            a2 += e2 * c0 + e3 * c1 + e4 * c2 + e5 * c3;
            a3 += e3 * c0 + e4 * c1 + e5 * c2 + e6 * c3;
            cur = nxt;
        }
    }
    if (wv > 0) {
        red[wv - 1][lane][0] = a0; red[wv - 1][lane][1] = a1;
        red[wv - 1][lane][2] = a2; red[wv - 1][lane][3] = a3;
    }
    __syncthreads();
    if (wv == 0) {
        a0 += red[0][lane][0] + red[1][lane][0] + red[2][lane][0];
        a1 += red[0][lane][1] + red[1][lane][1] + red[2][lane][1];
        a2 += red[0][lane][2] + red[1][lane][2] + red[2][lane][2];
        a3 += red[0][lane][3] + red[1][lane][3] + red[2][lane][3];
        double gb = (double)bias[0];
        double sd = sdot[b];
        double accs[4] = {a0, a1, a2, a3};
        int tb = t0 + base;
        for (int i = 0; i < 4; ++i) {
            int t = tb + i;
            if (t < LS_) gensig[(size_t)b * LS_ + t] = sd * ft[t] + gb + accs[i];
        }
    }
}

// ---------------- scan: i8-MFMA far + const-compare spec rounds, hoisted xb ----
// Waves 0..3 (scan): one wave per 16 chains. Waves 4..7 (prep): logit producers.
// NEAR: 4 rounds x 4 steps. Per round on-chain: 3-level dsel tree (8-entry Cc,
//   ages 4..6) -> 1 f64 sub -> 8 f64 cmps -> ballots -> SALU cascade.
//   Ages 8..15 AND age-7-for-j<=2 (they reference rounds <= E-2) are hoisted
//   TWO rounds early into pre_E = thr_E - xb78_E (latency hidden under a full
//   round). Age-7 for j==3 (references round E-1 bit 0) enters via
//   d7 = dand(tap7hi, -(nib&1)) right after the previous cascade (3 ops).
//   q16/q2n rebuilt from cascade S-masks by shifts: no QL-csel, no bpermute.
__global__ __launch_bounds__(512, 2) void k_scan(const double* __restrict__ gensig,
                                                 const float* __restrict__ u,
                                                 const float* __restrict__ iss,
                                                 const float* __restrict__ ff,
                                                 float* __restrict__ out) {
    __shared__ double farT_all[4][16 * 17];          // 8.5 KB (scan waves only)
    __shared__ double luring[2][4][4 * 64];          // 16 KB: [slot][scanwave][e*64+lane]
    int tid = threadIdx.x;
    int wv = tid >> 6, l = tid & 63;
    int swv = wv & 3;
    const bool isPrep = (wv >= 4);
    int gw = blockIdx.x * 4 + swv;
    int b = gw >> 3, rbase = (gw & 7) * 16;
    double* farT = &farT_all[swv][0];

    int lw = l & 15;
    int q  = l >> 4;
    int cn = l >> 2;
    int j  = l & 3;
    int jo = 16 + j;            // sbfe offset base: bit(16 + t - a) with t = 4e+j
    int sh4cn = cn * 4;
    int sh4lw = lw * 4;

    const unsigned long long COL0_ = 0x1111111111111111ull;
    const unsigned long long COL1_ = COL0_ << 1;
    const unsigned long long COL2_ = COL0_ << 2;
    const unsigned long long COL3_ = COL0_ << 3;
    const unsigned long long COL01_ = COL0_ | COL1_;

    const double* gs   = gensig + (size_t)b * LS_;
    const float*  up   = u + b * R_ + rbase + cn;
    float*        op   = out + ((size_t)(b * R_ + rbase + cn)) * NB_ + NF_;
    const float*  issb = iss + b * NF_;

    // scan-wave state
    unsigned long long W0 = 0, W1 = 0, W2 = 0, W3 = 0;
    v4i Bf[4][6];
    double tp8 = 0, tp9 = 0, tp10 = 0, tp11 = 0, tp12 = 0, tp13 = 0, tp14 = 0, tp15 = 0;
    double tap7lo = 0, tap7hi = 0;
    double SC1 = 0, SC2 = 0, SC3 = 0, SC4 = 0, SC5 = 0, SC6 = 0, SC7 = 0;
    double Cc0 = 0, Cc1 = 0, Cc2 = 0, Cc3 = 0, Cc4 = 0, Cc5 = 0, Cc6 = 0, Cc7 = 0;
    double thr0 = 0, thr1 = 0, thr2 = 0, thr3 = 0;
    double gprep = 0.0;
    // prep-wave state
    float ur0 = 0.f, ur1 = 0.f, ur2 = 0.f, ur3 = 0.f;

    if (!isPrep) {
        // ---- iss -> out[.., 0:250] ----
        for (int idx = l; idx < 16 * NF_; idx += 64) {
            int c = idx / NF_, k = idx - c * NF_;
            out[((size_t)(b * R_ + rbase + c)) * NB_ + k] = issb[k];
        }
        // ---- window: bit k = spike(t0-250+k) ----
        for (int k = 0; k < NF_; ++k) {
            unsigned long long bit = (issb[k] > 0.5f) ? 1ull : 0ull;
            if      (k <  64) W0 |= bit << k;
            else if (k < 128) W1 |= bit << (k - 64);
            else if (k < 192) W2 |= bit << (k - 128);
            else              W3 |= bit << (k - 192);
        }
        // ---- B: F[k][n] = ff[k-n]; 6 signed base-256 digit planes @2^48 ----
        int Bword[4][6][4];
#pragma unroll
        for (int kc = 0; kc < 4; ++kc)
#pragma unroll
            for (int p = 0; p < 6; ++p)
#pragma unroll
                for (int w = 0; w < 4; ++w) Bword[kc][p][w] = 0;
#pragma unroll
        for (int kc = 0; kc < 4; ++kc) {
#pragma unroll
            for (int jj = 0; jj < 16; ++jj) {
                int k = kc * 64 + q * 16 + jj;
                int idx = k - lw;
                long long v = 0;
                if (idx >= 0 && idx < NF_)
                    v = __double2ll_rn((double)ff[idx] * 281474976710656.0);   // * 2^48
#pragma unroll
                for (int p = 0; p < 6; ++p) {
                    int d = (int)((v + 128) & 255) - 128;
                    v = (v - (long long)d) >> 8;
                    Bword[kc][p][jj >> 2] |= (d & 255) << ((jj & 3) * 8);
                }
            }
        }
#pragma unroll
        for (int kc = 0; kc < 4; ++kc)
#pragma unroll
            for (int p = 0; p < 6; ++p) {
                v4i t; t.x = Bword[kc][p][0]; t.y = Bword[kc][p][1];
                t.z = Bword[kc][p][2]; t.w = Bword[kc][p][3];
                Bf[kc][p] = t;
            }
        // near taps, f64: age a -> ff[250-a]
        double T1d = (double)ff[249], T2d = (double)ff[248], T3d = (double)ff[247];
        double T4d = (double)ff[246], T5d = (double)ff[245], T6d = (double)ff[244];
        double T7d = (double)ff[243];
        tp8  = (double)ff[242]; tp9  = (double)ff[241];
        tp10 = (double)ff[240]; tp11 = (double)ff[239]; tp12 = (double)ff[238];
        tp13 = (double)ff[237]; tp14 = (double)ff[236]; tp15 = (double)ff[235];
        tap7lo = (j < 3) ? T7d : 0.0;     // age-7 for j<=2 lives in round E-2 (xb78)
        tap7hi = (j == 3) ? T7d : 0.0;    // age-7 for j==3 lives in round E-1 bit 0 (d7)
        // speculation compare constants (ages 1..3; bit0=T1,bit1=T2,bit2=T3)
        SC1 = T1d; SC2 = T2d; SC3 = T1d + T2d;
        SC4 = T3d; SC5 = T3d + T1d; SC6 = T3d + T2d; SC7 = (T3d + T2d) + T1d;
        // base select constants (ages 4..6; bit0=A4/T4, bit1=A5/T5, bit2=A6/T6)
        Cc0 = 0.0; Cc1 = T4d; Cc2 = T5d; Cc3 = T4d + T5d;
        Cc4 = T6d; Cc5 = T6d + T4d; Cc6 = T6d + T5d; Cc7 = (T6d + T5d) + T4d;
    } else {
        // ---- prep prologue: lu(0) -> slot0, lu(1) -> slot1, prefetch u(block 2) ----
        ur0 = up[(size_t)(0  + j) * BR_];
        ur1 = up[(size_t)(4  + j) * BR_];
        ur2 = up[(size_t)(8  + j) * BR_];
        ur3 = up[(size_t)(12 + j) * BR_];
        luring[0][swv][  0 + l] = logit_fast(ur0);
        luring[0][swv][ 64 + l] = logit_fast(ur1);
        luring[0][swv][128 + l] = logit_fast(ur2);
        luring[0][swv][192 + l] = logit_fast(ur3);
        ur0 = up[(size_t)(16 + j) * BR_];
        ur1 = up[(size_t)(20 + j) * BR_];
        ur2 = up[(size_t)(24 + j) * BR_];
        ur3 = up[(size_t)(28 + j) * BR_];
        luring[1][swv][  0 + l] = logit_fast(ur0);
        luring[1][swv][ 64 + l] = logit_fast(ur1);
        luring[1][swv][128 + l] = logit_fast(ur2);
        luring[1][swv][192 + l] = logit_fast(ur3);
        ur0 = up[(size_t)(32 + j) * BR_];
        ur1 = up[(size_t)(36 + j) * BR_];
        ur2 = up[(size_t)(40 + j) * BR_];
        ur3 = up[(size_t)(44 + j) * BR_];
    }

    // full-window far: fb[chain=q*4+r][step=lw] = gp + sum_k W[k]*ff[k-lw]
    auto do_far = [&](double gp) {
        unsigned long long Sarr[4] = {W0, W1, W2, W3};
        v4i accm[6];
#pragma unroll
        for (int p = 0; p < 6; ++p) accm[p] = (v4i){0, 0, 0, 0};
#pragma unroll
        for (int kc = 0; kc < 4; ++kc) {
            unsigned f = (unsigned)((Sarr[kc] >> (q * 16)) & 0xFFFFull);
            v4i av;
            av.x = (int)((((f      ) & 0xFu) * 0x00204081u) & 0x01010101u);
            av.y = (int)((((f >>  4) & 0xFu) * 0x00204081u) & 0x01010101u);
            av.z = (int)((((f >>  8) & 0xFu) * 0x00204081u) & 0x01010101u);
            av.w = (int)((((f >> 12) & 0xFu) * 0x00204081u) & 0x01010101u);
#pragma unroll
            for (int p = 0; p < 6; ++p)
                accm[p] = __builtin_amdgcn_mfma_i32_16x16x64_i8(av, Bf[kc][p], accm[p], 0, 0, 0);
        }
#pragma unroll
        for (int r = 0; r < 4; ++r) {
            int lo = accm[0][r] + accm[1][r] * 256 + accm[2][r] * 65536;
            int hi = accm[3][r] + accm[4][r] * 256 + accm[5][r] * 65536;
            double fb = gp + (double)lo * 0x1p-48 + (double)hi * 0x1p-24;
            farT[(q * 4 + r) * 17 + lw] = fb;
        }
    };

    // ages 7..15 (age-7 masked to j<=2) for round E; q16v bits = resolved steps
    auto xb78 = [&](int e4, unsigned q16v) -> double {
        unsigned qs = (q16v << 16) >> e4;
        double x = (dand(tap7lo, __builtin_amdgcn_sbfe((int)qs, jo - 7,  1)) +
                    dand(tp8,  __builtin_amdgcn_sbfe((int)qs, jo - 8,  1))) +
                   (dand(tp9,  __builtin_amdgcn_sbfe((int)qs, jo - 9,  1)) +
                    dand(tp10, __builtin_amdgcn_sbfe((int)qs, jo - 10, 1)));
        double y = (dand(tp11, __builtin_amdgcn_sbfe((int)qs, jo - 11, 1)) +
                    dand(tp12, __builtin_amdgcn_sbfe((int)qs, jo - 12, 1))) +
                   (dand(tp13, __builtin_amdgcn_sbfe((int)qs, jo - 13, 1)) +
                    dand(tp14, __builtin_amdgcn_sbfe((int)qs, jo - 14, 1)));
        return (x + y) + dand(tp15, __builtin_amdgcn_sbfe((int)qs, jo - 15, 1));
    };

    __syncthreads();   // A: prep's lu(0), lu(1) visible to scan waves

    if (!isPrep) {
        // ---- scan prologue: block 0 ----
        gprep = gs[lw];
        do_far(gprep);
        double lu0 = luring[0][swv][  0 + l];
        double lu1 = luring[0][swv][ 64 + l];
        double lu2 = luring[0][swv][128 + l];
        double lu3 = luring[0][swv][192 + l];
        __asm__ volatile("s_waitcnt lgkmcnt(0)" ::: "memory");
        thr0 = lu0 - farT[cn * 17 +  0 + j];
        thr1 = lu1 - farT[cn * 17 +  4 + j];
        thr2 = lu2 - farT[cn * 17 +  8 + j];
        thr3 = lu3 - farT[cn * 17 + 12 + j];
        { int tg = 16 + lw; if (tg > LS_ - 1) tg = LS_ - 1; gprep = gs[tg]; }
    }

    __syncthreads();   // B: scan's slot0 (lu(0)) reads done before prep overwrites it

// one 4-step round: PRE2 already includes -xb78 and -d7 adjustments
#define ROUND(PRE2, SOUT) { \
    double u0_ = dsel_ab(Cc0, Cc1, A4); \
    double u1_ = dsel_ab(Cc2, Cc3, A4); \
    double u2_ = dsel_ab(Cc4, Cc5, A4); \
    double u3_ = dsel_ab(Cc6, Cc7, A4); \
    double v0_ = dsel_ab(u0_, u1_, A5); \
    double v1_ = dsel_ab(u2_, u3_, A5); \
    double sel_ = dsel_ab(v0_, v1_, A6); \
    double rhs_ = (PRE2) - sel_; \
    unsigned long long Bm0 = __ballot(0.0 > rhs_); \
    unsigned long long Bm1 = __ballot(SC1 > rhs_); \
    unsigned long long Bm2 = __ballot(SC2 > rhs_); \
    unsigned long long Bm3 = __ballot(SC3 > rhs_); \
    unsigned long long Bm4 = __ballot(SC4 > rhs_); \
    unsigned long long Bm5 = __ballot(SC5 > rhs_); \
    unsigned long long Bm6 = __ballot(SC6 > rhs_); \
    unsigned long long Bm7 = __ballot(SC7 > rhs_); \
    unsigned long long a3p = P >> 1, a2p = P >> 2; \
    unsigned long long C0 = Bm0 ^ (a3p & (Bm4 ^ Bm0)); \
    unsigned long long C1 = Bm1 ^ (a3p & (Bm5 ^ Bm1)); \
    unsigned long long C2 = Bm2 ^ (a3p & (Bm6 ^ Bm2)); \
    unsigned long long C3 = Bm3 ^ (a3p & (Bm7 ^ Bm3)); \
    unsigned long long D0 = C0 ^ (a2p & (C2 ^ C0)); \
    unsigned long long D1 = C1 ^ (a2p & (C3 ^ C1)); \
    unsigned long long Dd = D1 ^ D0; \
    unsigned long long S = (D0 ^ ((P >> 3) & Dd)) & COL0_; \
    S |= (D0 ^ ((S << 1) & Dd)) & COL1_; \
    { unsigned long long a2s = S << 2; \
      unsigned long long D0b = C0 ^ (a2s & (C2 ^ C0)); \
      unsigned long long D1b = C1 ^ (a2s & (C3 ^ C1)); \
      S |= (D0b ^ ((S << 1) & (D1b ^ D0b))) & COL2_; } \
    { unsigned long long a3s = S << 3, a2s = S << 2; \
      unsigned long long C0c = Bm0 ^ (a3s & (Bm4 ^ Bm0)); \
      unsigned long long C1c = Bm1 ^ (a3s & (Bm5 ^ Bm1)); \
      unsigned long long C2c = Bm2 ^ (a3s & (Bm6 ^ Bm2)); \
      unsigned long long C3c = Bm3 ^ (a3s & (Bm7 ^ Bm3)); \
      unsigned long long D0c = C0c ^ (a2s & (C2c ^ C0c)); \
      unsigned long long D1c = C1c ^ (a2s & (C3c ^ C1c)); \
      S |= (D0c ^ ((S << 1) & (D1c ^ D0c))) & COL3_; } \
    (SOUT) = S; \
    A4 = S; \
    A5 = ((S << 1) & ~COL0_) | ((P >> 3) & COL0_); \
    A6 = ((S << 2) & ~COL01_) | ((P >> 2) & COL01_); \
    P = S; \
}

    int blk = 0;
    for (int t0 = 0; t0 < LS_; t0 += H_, ++blk) {
        if (!isPrep) {
            // ---- NEAR: 4 rounds; xb78 hoisted 2 rounds early, d7 1 round ----
            unsigned long long P = 0, A4 = 0, A5 = 0, A6 = 0;
            unsigned long long S0s, S1s, S2s, S3s;
            ROUND(thr0, S0s)
            unsigned nib0 = ((unsigned)(S0s >> sh4cn)) & 15u;
            unsigned q16 = nib0;
            double d7_1 = dand(tap7hi, -(int)(nib0 & 1u));
            double pre2 = thr2 - xb78(8, q16);             // needs round 0 only; hides under round 1
            ROUND(thr1 - d7_1, S1s)
            unsigned nib1 = ((unsigned)(S1s >> sh4cn)) & 15u;
            q16 |= nib1 << 4;
            double d7_2 = dand(tap7hi, -(int)(nib1 & 1u));
            double pre3 = thr3 - xb78(12, q16);            // needs rounds 0..1; hides under round 2
            ROUND(pre2 - d7_2, S2s)
            unsigned nib2 = ((unsigned)(S2s >> sh4cn)) & 15u;
            q16 |= nib2 << 8;
            double d7_3 = dand(tap7hi, -(int)(nib2 & 1u));
            ROUND(pre3 - d7_3, S3s)
            unsigned nib3 = ((unsigned)(S3s >> sh4cn)) & 15u;
            q16 |= nib3 << 12;
            unsigned q2 = q16;                             // bit i = spike(t0+i), chain cn

            // ---- store spikes ----
            int rem = LS_ - t0; if (rem > H_) rem = H_;
            int s0 = 4 * j;
            if (s0 + 3 < rem) {
                float4 o;
                o.x = (float)((q2 >> (s0    )) & 1u);
                o.y = (float)((q2 >> (s0 + 1)) & 1u);
                o.z = (float)((q2 >> (s0 + 2)) & 1u);
                o.w = (float)((q2 >> (s0 + 3)) & 1u);
                *(float4*)(op + t0 + s0) = o;
            } else {
#pragma unroll
                for (int e = 0; e < 4; ++e)
                    if (s0 + e < rem) op[t0 + s0 + e] = (float)((q2 >> (s0 + e)) & 1u);
            }

            if (t0 + H_ < LS_) {
                // chain lw's 16 new spike bits, rebuilt from cascade masks (no LDS)
                unsigned q2n32 = (((unsigned)(S0s >> sh4lw)) & 15u)
                               | ((((unsigned)(S1s >> sh4lw)) & 15u) << 4)
                               | ((((unsigned)(S2s >> sh4lw)) & 15u) << 8)
                               | ((((unsigned)(S3s >> sh4lw)) & 15u) << 12);

                // lu(blk+1) was written by prep last iteration; issue reads early
                double lu0 = luring[(blk + 1) & 1][swv][  0 + l];
                double lu1 = luring[(blk + 1) & 1][swv][ 64 + l];
                double lu2 = luring[(blk + 1) & 1][swv][128 + l];
                double lu3 = luring[(blk + 1) & 1][swv][192 + l];

                // advance per-chain window with chain lw's new spikes
                unsigned long long q2n = (unsigned long long)q2n32;
                W0 = (W0 >> 16) | (W1 << 48);
                W1 = (W1 >> 16) | (W2 << 48);
                W2 = (W2 >> 16) | (W3 << 48);
                W3 = (W3 >> 16) | (q2n << 42);

                do_far(gprep);                                  // block t0+16
                __asm__ volatile("s_waitcnt lgkmcnt(0)" ::: "memory");
                thr0 = lu0 - farT[cn * 17 +  0 + j];
                thr1 = lu1 - farT[cn * 17 +  4 + j];
                thr2 = lu2 - farT[cn * 17 +  8 + j];
                thr3 = lu3 - farT[cn * 17 + 12 + j];

                int tg = t0 + 32 + lw; if (tg > LS_ - 1) tg = LS_ - 1;
                gprep = gs[tg];
            }
        } else {
            // ---- prep: lu(blk+2) -> slot[blk&1]; prefetch u(block blk+3) ----
            if (blk <= NBLK_ - 3) {
                double lu0 = logit_fast(ur0), lu1 = logit_fast(ur1);
                double lu2 = logit_fast(ur2), lu3 = logit_fast(ur3);
                luring[blk & 1][swv][  0 + l] = lu0;
                luring[blk & 1][swv][ 64 + l] = lu1;
                luring[blk & 1][swv][128 + l] = lu2;
                luring[blk & 1][swv][192 + l] = lu3;
                if (blk <= NBLK_ - 4) {
                    int T = (blk + 3) * H_;
                    int t_;
                    t_ = T +  0 + j; if (t_ > LS_ - 1) t_ = LS_ - 1; ur0 = up[(size_t)t_ * BR_];
                    t_ = T +  4 + j; if (t_ > LS_ - 1) t_ = LS_ - 1; ur1 = up[(size_t)t_ * BR_];
                    t_ = T +  8 + j; if (t_ > LS_ - 1) t_ = LS_ - 1; ur2 = up[(size_t)t_ * BR_];
                    t_ = T + 12 + j; if (t_ > LS_ - 1) t_ = LS_ - 1; ur3 = up[(size_t)t_ * BR_];
                }
            }
        }
        __syncthreads();   // paces ring: write(t) | bar | read(t+1) | bar | overwrite(t+2)
    }
#undef ROUND
}

extern "C" void kernel_launch(void* const* d_in, const int* in_sizes, int n_in,
                              void* d_out, int out_size, void* d_ws, size_t ws_size,
                              hipStream_t stream) {
    const float* stim_spat = (const float*)d_in[0];   // (128,2048)
    const float* stim_time = (const float*)d_in[1];   // (2000,)
    const float* iss       = (const float*)d_in[2];   // (128,250)
    const float* cc        = (const float*)d_in[3];   // (128,16,2000)
    const float* sf        = (const float*)d_in[4];   // (2048,)
    const float* bias      = (const float*)d_in[5];   // (1,)
    const float* stf       = (const float*)d_in[6];   // (250,)
    const float* ff        = (const float*)d_in[7];   // (250,)
    const float* cf        = (const float*)d_in[8];   // (16,250)
    const float* u         = (const float*)d_in[9];   // (1750,128,128)
    (void)in_sizes; (void)n_in; (void)out_size; (void)ws_size;

    float* out = (float*)d_out;                       // (128,128,2000)

    double* ws     = (double*)d_ws;
    double* gensig = ws;                              // 128*1750 f64
    double* ft     = gensig + (size_t)B_ * LS_;       // 1751 f64
    double* sdot   = ft + NT_;                        // 128 f64

    k_pre  <<<135, 256, 0, stream>>>(stim_time, stf, stim_spat, sf, ft, sdot);
    k_coup <<<dim3(7, B_), 256, 0, stream>>>(cc, cf, sdot, ft, bias, gensig);
    k_scan <<<B_ * 2, 512, 0, stream>>>(gensig, u, iss, ff, out);
}

// Round 8
// 489.549 us; speedup vs baseline: 1.2894x; 1.0555x over previous
//
#include <hip/hip_runtime.h>
#include <math.h>

#define B_  128
#define P_  2048
#define NB_ 2000
#define NF_ 250
#define NC_ 16
#define R_  128
#define LS_ 1750   // NB-NF (len_sim)
#define NT_ 1751   // NB-NF+1
#define BR_ (B_ * R_)
#define H_  16     // steps per sub-block
#define NIT_ 55    // outer iterations of 32 steps (2 sub-blocks each)

typedef int v4i __attribute__((ext_vector_type(4)));

// ---- per-lane f64 2-way select: bit[lane] of m ? b : a ----
__device__ __forceinline__ double dsel_ab(double a, double b, unsigned long long m) {
    long long ab = __double_as_longlong(a), bb = __double_as_longlong(b);
    int rlo, rhi;
    asm("v_cndmask_b32 %0, %2, %4, %6\n\t"
        "v_cndmask_b32 %1, %3, %5, %6"
        : "=&v"(rlo), "=&v"(rhi)
        : "v"((int)ab), "v"((int)(ab >> 32)), "v"((int)bb), "v"((int)(bb >> 32)), "s"(m));
    return __longlong_as_double(((long long)(unsigned)rlo) | ((long long)rhi << 32));
}

// ---- f64 AND with 0/-1 int mask ----
__device__ __forceinline__ double dand(double t, int m) {
    return __longlong_as_double(__double_as_longlong(t) & (long long)m);
}

// ---- reciprocal: v_rcp_f64 + 1 NR (rel err ~1e-16) ----
__device__ __forceinline__ double rcp1(double b) {
    double r;
    asm("v_rcp_f64 %0, %1" : "=v"(r) : "v"(b));
    r = fma(fma(-b, r, 1.0), r, r);
    return r;
}

// ---- custom logit: log(u/(1-u)) f64 path + f32 tail poly, abs err < ~1e-9 ----
__device__ __forceinline__ double logit_fast(float uf) {
    double u = (double)uf;
    double v = 1.0 - u;                  // exact (u has 24-bit mantissa)
    double qd = u * rcp1(v);             // rel err ~2e-16
    long long bits = __double_as_longlong(qd);
    int e = (int)((bits >> 52) & 0x7FF) - 1023;
    double m = __longlong_as_double((bits & 0xFFFFFFFFFFFFFLL) | 0x3FF0000000000000LL);
    if (m > 1.4142135623730951) { m *= 0.5; e += 1; }   // m in [0.707,1.414]
    double s = (m - 1.0) * rcp1(m + 1.0);               // |s| <= 0.1716, (m-1) exact
    float zf = (float)(s * s);
    float Qf = fmaf(zf, fmaf(zf, fmaf(zf, fmaf(zf,
        0.09090909090909091f, 0.1111111111111111f),
        0.14285714285714285f), 0.2f), 0.3333333333333333f);
    double logm = fma(2.0 * s, (double)(zf * Qf), 2.0 * s);   // 2*atanh(s)
    return fma((double)e, 0.6931471805599453, logm);
}

// ---------------- fused: ft (blocks 0..6) + sdot (blocks 7..134) ----------------
__global__ __launch_bounds__(256) void k_pre(const float* __restrict__ st,
                                             const float* __restrict__ stf,
                                             const float* __restrict__ sp,
                                             const float* __restrict__ sf,
                                             double* __restrict__ ft,
                                             double* __restrict__ sdot) {
    if (blockIdx.x < 7) {
        int t = blockIdx.x * 256 + threadIdx.x;
        if (t >= NT_) return;
        double s = 0.0;
        for (int k = 0; k < NF_; ++k) s += (double)st[t + k] * (double)stf[k];
        ft[t] = s;
    } else {
        __shared__ double red[256];
        int b = blockIdx.x - 7;
        double s = 0.0;
        for (int p = threadIdx.x; p < P_; p += 256)
            s += (double)sp[(size_t)b * P_ + p] * (double)sf[p];
        red[threadIdx.x] = s;
        __syncthreads();
        for (int off = 128; off > 0; off >>= 1) {
            if (threadIdx.x < off) red[threadIdx.x] += red[threadIdx.x + off];
            __syncthreads();
        }
        if (threadIdx.x == 0) sdot[b] = red[0];
    }
}

// ---------------- gensig[b,t] = sdot[b]*ft[t] + bias + coup[b,t], f64 ----------------
__global__ __launch_bounds__(256) void k_coup(const float* __restrict__ cc,
                                              const float* __restrict__ cf,
                                              const double* __restrict__ sdot,
                                              const double* __restrict__ ft,
                                              const float* __restrict__ bias,
                                              double* __restrict__ gensig) {
    __shared__ __align__(16) float  ccs[NC_ * 512];   // 32 KB
    __shared__ __align__(16) double cfs[NC_ * 256];   // 32 KB
    __shared__ double red[3][64][4];                  // 6 KB
    int b = blockIdx.y, t0 = blockIdx.x * 256;
    int tid = threadIdx.x, lane = tid & 63, wv = tid >> 6;

    for (int idx = tid; idx < NC_ * 128; idx += 256) {
        int c = idx >> 7, j4 = (idx & 127) * 4, src = t0 + j4;
        const float* p = cc + ((size_t)b * NC_ + c) * NB_ + src;
        float4 v;
        if (src + 3 < NB_) v = *(const float4*)p;
        else {
            v.x = (src     < NB_) ? p[0] : 0.f;
            v.y = (src + 1 < NB_) ? p[1] : 0.f;
            v.z = (src + 2 < NB_) ? p[2] : 0.f;
            v.w = (src + 3 < NB_) ? p[3] : 0.f;
        }
        *(float4*)&ccs[c * 512 + j4] = v;
    }
    for (int idx = tid; idx < NC_ * 256; idx += 256) {
        int c = idx >> 8, k = idx & 255;
        cfs[idx] = (k < NF_) ? (double)cf[c * NF_ + k] : 0.0;
    }
    __syncthreads();

    double a0 = 0, a1 = 0, a2 = 0, a3 = 0;
    int base = lane * 4;
    for (int c = wv; c < NC_; c += 4) {
        const float*  row  = &ccs[c * 512];
        const double* crow = &cfs[c * 256];
        float4 cur = *(const float4*)&row[base];
        for (int k4 = 0; k4 < 252; k4 += 4) {
            float4 nxt = *(const float4*)&row[base + k4 + 4];
            double e0 = cur.x, e1 = cur.y, e2 = cur.z, e3 = cur.w;
            double e4 = nxt.x, e5 = nxt.y, e6 = nxt.z;
            double c0 = crow[k4], c1 = crow[k4 + 1], c2 = crow[k4 + 2], c3 = crow[k4 + 3];
            a0 += e0 * c0 + e1 * c1 + e2 * c2 + e3 * c3;
            a1 += e1 * c0 + e2 * c1 + e3 * c2 + e4 * c3;
            a2 += e2 * c0 + e3 * c1 + e4 * c2 + e5 * c3;
            a3 += e3 * c0 + e4 * c1 + e5 * c2 + e6 * c3;
            cur = nxt;
        }
    }
    if (wv > 0) {
        red[wv - 1][lane][0] = a0; red[wv - 1][lane][1] = a1;
        red[wv - 1][lane][2] = a2; red[wv - 1][lane][3] = a3;
    }
    __syncthreads();
    if (wv == 0) {
        a0 += red[0][lane][0] + red[1][lane][0] + red[2][lane][0];
        a1 += red[0][lane][1] + red[1][lane][1] + red[2][lane][1];
        a2 += red[0][lane][2] + red[1][lane][2] + red[2][lane][2];
        a3 += red[0][lane][3] + red[1][lane][3] + red[2][lane][3];
        double gb = (double)bias[0];
        double sd = sdot[b];
        double accs[4] = {a0, a1, a2, a3};
        int tb = t0 + base;
        for (int i = 0; i < 4; ++i) {
            int t = tb + i;
            if (t < LS_) gensig[(size_t)b * LS_ + t] = sd * ft[t] + gb + accs[i];
        }
    }
}

// ---------------- scan: H=32 iterations, 6-slot lu ring, issue-early loads ----
// Waves 0..3 (scan): one wave per 16 chains. Waves 4..7 (prep): logit producers.
// Two 16-step sub-blocks per outer iteration; ONE __syncthreads per 32 steps
// (the compiler's vmcnt(0)-drain before s_barrier was the hidden per-iteration
// tax). Prep issues next-iteration u loads at iteration TOP (2 generations of
// regs) so HBM latency hides under ~32 logits of compute. luring ring: slot =
// blk % 6; prep produces blocks 2it+4, 2it+5; scan consumes 2it+1, 2it+2 -
// all residues distinct mod 6, every write->read / read->overwrite pair is
// separated by >=1 barrier. Near/far/tail math identical to r7 (bit-exact).
__global__ __launch_bounds__(512, 2) void k_scan(const double* __restrict__ gensig,
                                                 const float* __restrict__ u,
                                                 const float* __restrict__ iss,
                                                 const float* __restrict__ ff,
                                                 float* __restrict__ out) {
    __shared__ double farT_all[4][16 * 17];          // 8.5 KB (scan waves only)
    __shared__ double luring[6][4][4 * 64];          // 48 KB: [slot][scanwave][e*64+lane]
    int tid = threadIdx.x;
    int wv = tid >> 6, l = tid & 63;
    int swv = wv & 3;
    const bool isPrep = (wv >= 4);
    int gw = blockIdx.x * 4 + swv;
    int b = gw >> 3, rbase = (gw & 7) * 16;
    double* farT = &farT_all[swv][0];

    int lw = l & 15;
    int q  = l >> 4;
    int cn = l >> 2;
    int j  = l & 3;
    int jo = 16 + j;            // sbfe offset base: bit(16 + t - a) with t = 4e+j
    int sh4cn = cn * 4;
    int sh4lw = lw * 4;

    const unsigned long long COL0_ = 0x1111111111111111ull;
    const unsigned long long COL1_ = COL0_ << 1;
    const unsigned long long COL2_ = COL0_ << 2;
    const unsigned long long COL3_ = COL0_ << 3;
    const unsigned long long COL01_ = COL0_ | COL1_;

    const double* gs   = gensig + (size_t)b * LS_;
    const float*  up   = u + b * R_ + rbase + cn;
    float*        op   = out + ((size_t)(b * R_ + rbase + cn)) * NB_ + NF_;
    const float*  issb = iss + b * NF_;

    // scan-wave state
    unsigned long long W0 = 0, W1 = 0, W2 = 0, W3 = 0;
    v4i Bf[4][6];
    double tp8 = 0, tp9 = 0, tp10 = 0, tp11 = 0, tp12 = 0, tp13 = 0, tp14 = 0, tp15 = 0;
    double tap7lo = 0, tap7hi = 0;
    double SC1 = 0, SC2 = 0, SC3 = 0, SC4 = 0, SC5 = 0, SC6 = 0, SC7 = 0;
    double Cc0 = 0, Cc1 = 0, Cc2 = 0, Cc3 = 0, Cc4 = 0, Cc5 = 0, Cc6 = 0, Cc7 = 0;
    double thr0 = 0, thr1 = 0, thr2 = 0, thr3 = 0;
    double gprep = 0.0;
    int rA = 1, rB = 2;          // scan read slots for blocks 2it+1, 2it+2
    // prep-wave state: two generations of u regs
    float uA0 = 0.f, uA1 = 0.f, uA2 = 0.f, uA3 = 0.f;
    float uB0 = 0.f, uB1 = 0.f, uB2 = 0.f, uB3 = 0.f;
    int sA = 4, sB = 5;          // prep write slots for blocks 2it+4, 2it+5

    if (!isPrep) {
        // ---- iss -> out[.., 0:250] ----
        for (int idx = l; idx < 16 * NF_; idx += 64) {
            int c = idx / NF_, k = idx - c * NF_;
            out[((size_t)(b * R_ + rbase + c)) * NB_ + k] = issb[k];
        }
        // ---- window: bit k = spike(t0-250+k) ----
        for (int k = 0; k < NF_; ++k) {
            unsigned long long bit = (issb[k] > 0.5f) ? 1ull : 0ull;
            if      (k <  64) W0 |= bit << k;
            else if (k < 128) W1 |= bit << (k - 64);
            else if (k < 192) W2 |= bit << (k - 128);
            else              W3 |= bit << (k - 192);
        }
        // ---- B: F[k][n] = ff[k-n]; 6 signed base-256 digit planes @2^48 ----
        int Bword[4][6][4];
#pragma unroll
        for (int kc = 0; kc < 4; ++kc)
#pragma unroll
            for (int p = 0; p < 6; ++p)
#pragma unroll
                for (int w = 0; w < 4; ++w) Bword[kc][p][w] = 0;
#pragma unroll
        for (int kc = 0; kc < 4; ++kc) {
#pragma unroll
            for (int jj = 0; jj < 16; ++jj) {
                int k = kc * 64 + q * 16 + jj;
                int idx = k - lw;
                long long v = 0;
                if (idx >= 0 && idx < NF_)
                    v = __double2ll_rn((double)ff[idx] * 281474976710656.0);   // * 2^48
#pragma unroll
                for (int p = 0; p < 6; ++p) {
                    int d = (int)((v + 128) & 255) - 128;
                    v = (v - (long long)d) >> 8;
                    Bword[kc][p][jj >> 2] |= (d & 255) << ((jj & 3) * 8);
                }
            }
        }
#pragma unroll
        for (int kc = 0; kc < 4; ++kc)
#pragma unroll
            for (int p = 0; p < 6; ++p) {
                v4i t; t.x = Bword[kc][p][0]; t.y = Bword[kc][p][1];
                t.z = Bword[kc][p][2]; t.w = Bword[kc][p][3];
                Bf[kc][p] = t;
            }
        // near taps, f64: age a -> ff[250-a]
        double T1d = (double)ff[249], T2d = (double)ff[248], T3d = (double)ff[247];
        double T4d = (double)ff[246], T5d = (double)ff[245], T6d = (double)ff[244];
        double T7d = (double)ff[243];
        tp8  = (double)ff[242]; tp9  = (double)ff[241];
        tp10 = (double)ff[240]; tp11 = (double)ff[239]; tp12 = (double)ff[238];
        tp13 = (double)ff[237]; tp14 = (double)ff[236]; tp15 = (double)ff[235];
        tap7lo = (j < 3) ? T7d : 0.0;     // age-7 for j<=2 lives in round E-2 (xb78)
        tap7hi = (j == 3) ? T7d : 0.0;    // age-7 for j==3 lives in round E-1 bit 0 (d7)
        // speculation compare constants (ages 1..3; bit0=T1,bit1=T2,bit2=T3)
        SC1 = T1d; SC2 = T2d; SC3 = T1d + T2d;
        SC4 = T3d; SC5 = T3d + T1d; SC6 = T3d + T2d; SC7 = (T3d + T2d) + T1d;
        // base select constants (ages 4..6; bit0=A4/T4, bit1=A5/T5, bit2=A6/T6)
        Cc0 = 0.0; Cc1 = T4d; Cc2 = T5d; Cc3 = T4d + T5d;
        Cc4 = T6d; Cc5 = T6d + T4d; Cc6 = T6d + T5d; Cc7 = (T6d + T5d) + T4d;
    } else {
        // ---- prep prologue: lu(0..3) -> slots 0..3; prefetch u(blocks 4,5) ----
        float x0, x1, x2, x3, y0, y1, y2, y3;
        x0 = up[(size_t)(0  + j) * BR_];  x1 = up[(size_t)(4  + j) * BR_];
        x2 = up[(size_t)(8  + j) * BR_];  x3 = up[(size_t)(12 + j) * BR_];
        y0 = up[(size_t)(16 + j) * BR_];  y1 = up[(size_t)(20 + j) * BR_];
        y2 = up[(size_t)(24 + j) * BR_];  y3 = up[(size_t)(28 + j) * BR_];
        luring[0][swv][  0 + l] = logit_fast(x0);
        luring[0][swv][ 64 + l] = logit_fast(x1);
        luring[0][swv][128 + l] = logit_fast(x2);
        luring[0][swv][192 + l] = logit_fast(x3);
        luring[1][swv][  0 + l] = logit_fast(y0);
        luring[1][swv][ 64 + l] = logit_fast(y1);
        luring[1][swv][128 + l] = logit_fast(y2);
        luring[1][swv][192 + l] = logit_fast(y3);
        x0 = up[(size_t)(32 + j) * BR_];  x1 = up[(size_t)(36 + j) * BR_];
        x2 = up[(size_t)(40 + j) * BR_];  x3 = up[(size_t)(44 + j) * BR_];
        y0 = up[(size_t)(48 + j) * BR_];  y1 = up[(size_t)(52 + j) * BR_];
        y2 = up[(size_t)(56 + j) * BR_];  y3 = up[(size_t)(60 + j) * BR_];
        luring[2][swv][  0 + l] = logit_fast(x0);
        luring[2][swv][ 64 + l] = logit_fast(x1);
        luring[2][swv][128 + l] = logit_fast(x2);
        luring[2][swv][192 + l] = logit_fast(x3);
        luring[3][swv][  0 + l] = logit_fast(y0);
        luring[3][swv][ 64 + l] = logit_fast(y1);
        luring[3][swv][128 + l] = logit_fast(y2);
        luring[3][swv][192 + l] = logit_fast(y3);
        uA0 = up[(size_t)(64 + j) * BR_]; uA1 = up[(size_t)(68 + j) * BR_];
        uA2 = up[(size_t)(72 + j) * BR_]; uA3 = up[(size_t)(76 + j) * BR_];
        uB0 = up[(size_t)(80 + j) * BR_]; uB1 = up[(size_t)(84 + j) * BR_];
        uB2 = up[(size_t)(88 + j) * BR_]; uB3 = up[(size_t)(92 + j) * BR_];
    }

    // full-window far: fb[chain=q*4+r][step=lw] = gp + sum_k W[k]*ff[k-lw]
    auto do_far = [&](double gp) {
        unsigned long long Sarr[4] = {W0, W1, W2, W3};
        v4i accm[6];
#pragma unroll
        for (int p = 0; p < 6; ++p) accm[p] = (v4i){0, 0, 0, 0};
#pragma unroll
        for (int kc = 0; kc < 4; ++kc) {
            unsigned f = (unsigned)((Sarr[kc] >> (q * 16)) & 0xFFFFull);
            v4i av;
            av.x = (int)((((f      ) & 0xFu) * 0x00204081u) & 0x01010101u);
            av.y = (int)((((f >>  4) & 0xFu) * 0x00204081u) & 0x01010101u);
            av.z = (int)((((f >>  8) & 0xFu) * 0x00204081u) & 0x01010101u);
            av.w = (int)((((f >> 12) & 0xFu) * 0x00204081u) & 0x01010101u);
#pragma unroll
            for (int p = 0; p < 6; ++p)
                accm[p] = __builtin_amdgcn_mfma_i32_16x16x64_i8(av, Bf[kc][p], accm[p], 0, 0, 0);
        }
#pragma unroll
        for (int r = 0; r < 4; ++r) {
            int lo = accm[0][r] + accm[1][r] * 256 + accm[2][r] * 65536;
            int hi = accm[3][r] + accm[4][r] * 256 + accm[5][r] * 65536;
            double fb = gp + (double)lo * 0x1p-48 + (double)hi * 0x1p-24;
            farT[(q * 4 + r) * 17 + lw] = fb;
        }
    };

    // ages 7..15 (age-7 masked to j<=2) for round E; q16v bits = resolved steps
    auto xb78 = [&](int e4, unsigned q16v) -> double {
        unsigned qs = (q16v << 16) >> e4;
        double x = (dand(tap7lo, __builtin_amdgcn_sbfe((int)qs, jo - 7,  1)) +
                    dand(tp8,  __builtin_amdgcn_sbfe((int)qs, jo - 8,  1))) +
                   (dand(tp9,  __builtin_amdgcn_sbfe((int)qs, jo - 9,  1)) +
                    dand(tp10, __builtin_amdgcn_sbfe((int)qs, jo - 10, 1)));
        double y = (dand(tp11, __builtin_amdgcn_sbfe((int)qs, jo - 11, 1)) +
                    dand(tp12, __builtin_amdgcn_sbfe((int)qs, jo - 12, 1))) +
                   (dand(tp13, __builtin_amdgcn_sbfe((int)qs, jo - 13, 1)) +
                    dand(tp14, __builtin_amdgcn_sbfe((int)qs, jo - 14, 1)));
        return (x + y) + dand(tp15, __builtin_amdgcn_sbfe((int)qs, jo - 15, 1));
    };

    __syncthreads();   // P: prep's lu(0..3) visible; prep's first in-loop writes
                       //    are slots 4,5 (blocks 4,5) - no conflict with scan
                       //    prologue/iter-0 reads (slots 0,1,2).

    if (!isPrep) {
        // ---- scan prologue: block 0 ----
        gprep = gs[lw];
        do_far(gprep);
        double lu0 = luring[0][swv][  0 + l];
        double lu1 = luring[0][swv][ 64 + l];
        double lu2 = luring[0][swv][128 + l];
        double lu3 = luring[0][swv][192 + l];
        __asm__ volatile("s_waitcnt lgkmcnt(0)" ::: "memory");
        thr0 = lu0 - farT[cn * 17 +  0 + j];
        thr1 = lu1 - farT[cn * 17 +  4 + j];
        thr2 = lu2 - farT[cn * 17 +  8 + j];
        thr3 = lu3 - farT[cn * 17 + 12 + j];
        gprep = gs[16 + lw];   // g for block 1 (far in first tail)
    }

// one 4-step round: PRE2 already includes -xb78 and -d7 adjustments
#define ROUND(PRE2, SOUT) { \
    double u0_ = dsel_ab(Cc0, Cc1, A4); \
    double u1_ = dsel_ab(Cc2, Cc3, A4); \
    double u2_ = dsel_ab(Cc4, Cc5, A4); \
    double u3_ = dsel_ab(Cc6, Cc7, A4); \
    double v0_ = dsel_ab(u0_, u1_, A5); \
    double v1_ = dsel_ab(u2_, u3_, A5); \
    double sel_ = dsel_ab(v0_, v1_, A6); \
    double rhs_ = (PRE2) - sel_; \
    unsigned long long Bm0 = __ballot(0.0 > rhs_); \
    unsigned long long Bm1 = __ballot(SC1 > rhs_); \
    unsigned long long Bm2 = __ballot(SC2 > rhs_); \
    unsigned long long Bm3 = __ballot(SC3 > rhs_); \
    unsigned long long Bm4 = __ballot(SC4 > rhs_); \
    unsigned long long Bm5 = __ballot(SC5 > rhs_); \
    unsigned long long Bm6 = __ballot(SC6 > rhs_); \
    unsigned long long Bm7 = __ballot(SC7 > rhs_); \
    unsigned long long a3p = P >> 1, a2p = P >> 2; \
    unsigned long long C0 = Bm0 ^ (a3p & (Bm4 ^ Bm0)); \
    unsigned long long C1 = Bm1 ^ (a3p & (Bm5 ^ Bm1)); \
    unsigned long long C2 = Bm2 ^ (a3p & (Bm6 ^ Bm2)); \
    unsigned long long C3 = Bm3 ^ (a3p & (Bm7 ^ Bm3)); \
    unsigned long long D0 = C0 ^ (a2p & (C2 ^ C0)); \
    unsigned long long D1 = C1 ^ (a2p & (C3 ^ C1)); \
    unsigned long long Dd = D1 ^ D0; \
    unsigned long long S = (D0 ^ ((P >> 3) & Dd)) & COL0_; \
    S |= (D0 ^ ((S << 1) & Dd)) & COL1_; \
    { unsigned long long a2s = S << 2; \
      unsigned long long D0b = C0 ^ (a2s & (C2 ^ C0)); \
      unsigned long long D1b = C1 ^ (a2s & (C3 ^ C1)); \
      S |= (D0b ^ ((S << 1) & (D1b ^ D0b))) & COL2_; } \
    { unsigned long long a3s = S << 3, a2s = S << 2; \
      unsigned long long C0c = Bm0 ^ (a3s & (Bm4 ^ Bm0)); \
      unsigned long long C1c = Bm1 ^ (a3s & (Bm5 ^ Bm1)); \
      unsigned long long C2c = Bm2 ^ (a3s & (Bm6 ^ Bm2)); \
      unsigned long long C3c = Bm3 ^ (a3s & (Bm7 ^ Bm3)); \
      unsigned long long D0c = C0c ^ (a2s & (C2c ^ C0c)); \
      unsigned long long D1c = C1c ^ (a2s & (C3c ^ C1c)); \
      S |= (D0c ^ ((S << 1) & (D1c ^ D0c))) & COL3_; } \
    (SOUT) = S; \
    A4 = S; \
    A5 = ((S << 1) & ~COL0_) | ((P >> 3) & COL0_); \
    A6 = ((S << 2) & ~COL01_) | ((P >> 2) & COL01_); \
    P = S; \
}

    // one 16-step sub-block: near rounds + stores + (optional) far/thr tail
    auto sub = [&](int t0s, int rslot, bool more) {
        unsigned long long P = 0, A4 = 0, A5 = 0, A6 = 0;
        unsigned long long S0s, S1s, S2s, S3s;
        ROUND(thr0, S0s)
        unsigned nib0 = ((unsigned)(S0s >> sh4cn)) & 15u;
        unsigned q16 = nib0;
        double d7_1 = dand(tap7hi, -(int)(nib0 & 1u));
        double pre2 = thr2 - xb78(8, q16);             // hides under round 1
        ROUND(thr1 - d7_1, S1s)
        unsigned nib1 = ((unsigned)(S1s >> sh4cn)) & 15u;
        q16 |= nib1 << 4;
        double d7_2 = dand(tap7hi, -(int)(nib1 & 1u));
        double pre3 = thr3 - xb78(12, q16);            // hides under round 2
        ROUND(pre2 - d7_2, S2s)
        unsigned nib2 = ((unsigned)(S2s >> sh4cn)) & 15u;
        q16 |= nib2 << 8;
        double d7_3 = dand(tap7hi, -(int)(nib2 & 1u));
        ROUND(pre3 - d7_3, S3s)
        unsigned nib3 = ((unsigned)(S3s >> sh4cn)) & 15u;
        q16 |= nib3 << 12;
        unsigned q2 = q16;                             // bit i = spike(t0s+i), chain cn

        // ---- store spikes ----
        int rem = LS_ - t0s; if (rem > H_) rem = H_;
        int s0 = 4 * j;
        if (s0 + 3 < rem) {
            float4 o;
            o.x = (float)((q2 >> (s0    )) & 1u);
            o.y = (float)((q2 >> (s0 + 1)) & 1u);
            o.z = (float)((q2 >> (s0 + 2)) & 1u);
            o.w = (float)((q2 >> (s0 + 3)) & 1u);
            *(float4*)(op + t0s + s0) = o;
        } else {
#pragma unroll
            for (int e = 0; e < 4; ++e)
                if (s0 + e < rem) op[t0s + s0 + e] = (float)((q2 >> (s0 + e)) & 1u);
        }

        if (more) {
            // chain lw's 16 new spike bits, rebuilt from cascade masks (no LDS)
            unsigned q2n32 = (((unsigned)(S0s >> sh4lw)) & 15u)
                           | ((((unsigned)(S1s >> sh4lw)) & 15u) << 4)
                           | ((((unsigned)(S2s >> sh4lw)) & 15u) << 8)
                           | ((((unsigned)(S3s >> sh4lw)) & 15u) << 12);

            // lu(block(t0s)+1) from ring; issue reads early
            double lu0 = luring[rslot][swv][  0 + l];
            double lu1 = luring[rslot][swv][ 64 + l];
            double lu2 = luring[rslot][swv][128 + l];
            double lu3 = luring[rslot][swv][192 + l];

            // advance per-chain window
            unsigned long long q2n = (unsigned long long)q2n32;
            W0 = (W0 >> 16) | (W1 << 48);
            W1 = (W1 >> 16) | (W2 << 48);
            W2 = (W2 >> 16) | (W3 << 48);
            W3 = (W3 >> 16) | (q2n << 42);

            do_far(gprep);                                  // far for block(t0s)+1
            __asm__ volatile("s_waitcnt lgkmcnt(0)" ::: "memory");
            thr0 = lu0 - farT[cn * 17 +  0 + j];
            thr1 = lu1 - farT[cn * 17 +  4 + j];
            thr2 = lu2 - farT[cn * 17 +  8 + j];
            thr3 = lu3 - farT[cn * 17 + 12 + j];

            int tg = t0s + 32 + lw; if (tg > LS_ - 1) tg = LS_ - 1;
            gprep = gs[tg];                                 // g for block(t0s)+2
        }
    };

    for (int it = 0; it < NIT_; ++it) {
        if (!isPrep) {
            sub(32 * it,      rA, true);       // block 2it   -> thr(2it+1)
            sub(32 * it + 16, rB, it < 54);    // block 2it+1 -> thr(2it+2)
            rA += 2; if (rA >= 6) rA -= 6;
            rB += 2; if (rB >= 6) rB -= 6;
        } else {
            // ---- issue next-iteration u loads FIRST (cover = 32 logits) ----
            int TL0 = (2 * it + 6) * H_;
            int t_;
            float na0, na1, na2, na3, nb0, nb1, nb2, nb3;
            t_ = TL0 +  0 + j; if (t_ > LS_ - 1) t_ = LS_ - 1; na0 = up[(size_t)t_ * BR_];
            t_ = TL0 +  4 + j; if (t_ > LS_ - 1) t_ = LS_ - 1; na1 = up[(size_t)t_ * BR_];
            t_ = TL0 +  8 + j; if (t_ > LS_ - 1) t_ = LS_ - 1; na2 = up[(size_t)t_ * BR_];
            t_ = TL0 + 12 + j; if (t_ > LS_ - 1) t_ = LS_ - 1; na3 = up[(size_t)t_ * BR_];
            t_ = TL0 + 16 + j; if (t_ > LS_ - 1) t_ = LS_ - 1; nb0 = up[(size_t)t_ * BR_];
            t_ = TL0 + 20 + j; if (t_ > LS_ - 1) t_ = LS_ - 1; nb1 = up[(size_t)t_ * BR_];
            t_ = TL0 + 24 + j; if (t_ > LS_ - 1) t_ = LS_ - 1; nb2 = up[(size_t)t_ * BR_];
            t_ = TL0 + 28 + j; if (t_ > LS_ - 1) t_ = LS_ - 1; nb3 = up[(size_t)t_ * BR_];

            if (it <= 52) {   // produce lu(2it+4), lu(2it+5); last needed = lu(109) at it=52
                luring[sA][swv][  0 + l] = logit_fast(uA0);
                luring[sA][swv][ 64 + l] = logit_fast(uA1);
                luring[sA][swv][128 + l] = logit_fast(uA2);
                luring[sA][swv][192 + l] = logit_fast(uA3);
                luring[sB][swv][  0 + l] = logit_fast(uB0);
                luring[sB][swv][ 64 + l] = logit_fast(uB1);
                luring[sB][swv][128 + l] = logit_fast(uB2);
                luring[sB][swv][192 + l] = logit_fast(uB3);
            }
            uA0 = na0; uA1 = na1; uA2 = na2; uA3 = na3;
            uB0 = nb0; uB1 = nb1; uB2 = nb2; uB3 = nb3;
            sA += 2; if (sA >= 6) sA -= 6;
            sB += 2; if (sB >= 6) sB -= 6;
        }
        __syncthreads();   // one barrier per 32 steps
    }
#undef ROUND
}

extern "C" void kernel_launch(void* const* d_in, const int* in_sizes, int n_in,
                              void* d_out, int out_size, void* d_ws, size_t ws_size,
                              hipStream_t stream) {
    const float* stim_spat = (const float*)d_in[0];   // (128,2048)
    const float* stim_time = (const float*)d_in[1];   // (2000,)
    const float* iss       = (const float*)d_in[2];   // (128,250)
    const float* cc        = (const float*)d_in[3];   // (128,16,2000)
    const float* sf        = (const float*)d_in[4];   // (2048,)
    const float* bias      = (const float*)d_in[5];   // (1,)
    const float* stf       = (const float*)d_in[6];   // (250,)
    const float* ff        = (const float*)d_in[7];   // (250,)
    const float* cf        = (const float*)d_in[8];   // (16,250)
    const float* u         = (const float*)d_in[9];   // (1750,128,128)
    (void)in_sizes; (void)n_in; (void)out_size; (void)ws_size;

    float* out = (float*)d_out;                       // (128,128,2000)

    double* ws     = (double*)d_ws;
    double* gensig = ws;                              // 128*1750 f64
    double* ft     = gensig + (size_t)B_ * LS_;       // 1751 f64
    double* sdot   = ft + NT_;                        // 128 f64

    k_pre  <<<135, 256, 0, stream>>>(stim_time, stf, stim_spat, sf, ft, sdot);
    k_coup <<<dim3(7, B_), 256, 0, stream>>>(cc, cf, sdot, ft, bias, gensig);
    k_scan <<<B_ * 2, 512, 0, stream>>>(gensig, u, iss, ff, out);
}